// Round 2
// baseline (312.068 us; speedup 1.0000x reference)
//
#include <hip/hip_runtime.h>
#include <math.h>

#define NUM_H 256
#define NP    64        // poles per h
#define LL    8192      // sequence length
#define NHALF 4096      // LL/2 (complex FFT size)
#define NF    4097      // rfft bins
#define NT    1024      // threads per block

__global__ __launch_bounds__(NT)
void ssk_nplr_kernel(const float* __restrict__ w_ri,
                     const float* __restrict__ p_ri,
                     const float* __restrict__ q_ri,
                     const float* __restrict__ B_ri,
                     const float* __restrict__ C_ri,
                     const float* __restrict__ log_dt,
                     float* __restrict__ out)
{
    __shared__ float4 s_wd[NP];        // (-wr*dt, wi*dt, (wr*dt)^2, 0)
    __shared__ float4 s_v[NP * 2];     // {v00r,v00i,v01r,v01i},{v10r,v10i,v11r,v11i}
    __shared__ float2 s_G[NF];         // rfft spectrum; reused as FFT ping-pong buf B
    __shared__ float2 s_Z[NHALF];      // FFT ping-pong buf A
    __shared__ float2 s_T4[2048];      // exp(+2pi i j/4096), j<2048  (FFT twiddles)
    __shared__ float2 s_T8[2048];      // exp(+2pi i k/8192), k<2048  (packing twiddles)

    const int h   = blockIdx.x;
    const int tid = threadIdx.x;
    const float dt = expf(log_dt[h]);

    // ---- Phase 0a: twiddle tables ----
    for (int j = tid; j < 2048; j += NT) {
        float s, c;
        sincosf(1.5339807878856412e-3f * (float)j, &s, &c);   // 2pi/4096
        s_T4[j] = make_float2(c, s);
        sincosf(7.6699039394282061e-4f * (float)j, &s, &c);   // 2pi/8192
        s_T8[j] = make_float2(c, s);
    }

    // ---- Phase 0b: per-h small data ----
    if (tid < NP) {
        const int n = tid;
        const float2 w = ((const float2*)w_ri)[h * NP + n];
        const float2 p = ((const float2*)p_ri)[h * NP + n];
        const float2 q = ((const float2*)q_ri)[h * NP + n];
        const float2 B = ((const float2*)B_ri)[h * NP + n];
        const float2 C = ((const float2*)C_ri)[h * NP + n];
        const float wr = w.x * dt, wi = w.y * dt;
        s_wd[n] = make_float4(-wr, wi, wr * wr, 0.f);
        float4 vA, vB;
        vA.x = B.x * C.x + B.y * C.y;  vA.y = B.y * C.x - B.x * C.y;  // B*conj(C)
        vA.z = p.x * C.x + p.y * C.y;  vA.w = p.y * C.x - p.x * C.y;  // p*conj(C)
        vB.x = B.x * q.x + B.y * q.y;  vB.y = B.y * q.x - B.x * q.y;  // B*conj(q)
        vB.z = p.x * q.x + p.y * q.y;  vB.w = p.y * q.x - p.x * q.y;  // p*conj(q)
        s_v[2 * n]     = vA;
        s_v[2 * n + 1] = vB;
    }
    __syncthreads();

    // ---- Phase 1: Cauchy sum, 4 l-points per thread in registers ----
    // z = 2i*tan(pi*l/L)  (purely imaginary);  2/(1+nodes) = 1 + i*tan(pi*l/L)
    float yv[4];
    float acc[4][8];
    #pragma unroll
    for (int li = 0; li < 4; ++li) {
        const int l = tid + NT * li;
        float s, c;
        sincosf(3.8349519697141031e-4f * (float)l, &s, &c);   // pi/8192
        yv[li] = 2.0f * s * __builtin_amdgcn_rcpf(c);
        #pragma unroll
        for (int t = 0; t < 8; ++t) acc[li][t] = 0.f;
    }
    #pragma unroll 2
    for (int n = 0; n < NP; ++n) {
        const float4 wd = s_wd[n];
        const float4 vA = s_v[2 * n];
        const float4 vB = s_v[2 * n + 1];
        #pragma unroll
        for (int li = 0; li < 4; ++li) {
            const float y  = yv[li];
            const float t1 = y - wd.y, t2 = y + wd.y;
            const float i1 = __builtin_amdgcn_rcpf(fmaf(t1, t1, wd.z));
            const float i2 = __builtin_amdgcn_rcpf(fmaf(t2, t2, wd.z));
            const float u1 = t1 * i1, u2 = t2 * i2;
            const float Sr = wd.x * (i1 + i2);
            const float Si = -(u1 + u2);
            const float Dr = u1 - u2;
            const float Di = wd.x * (i1 - i2);
            acc[li][0] += vA.x * Sr + vA.y * Dr;
            acc[li][1] += vA.x * Si + vA.y * Di;
            acc[li][2] += vA.z * Sr + vA.w * Dr;
            acc[li][3] += vA.z * Si + vA.w * Di;
            acc[li][4] += vB.x * Sr + vB.y * Dr;
            acc[li][5] += vB.x * Si + vB.y * Di;
            acc[li][6] += vB.z * Sr + vB.w * Dr;
            acc[li][7] += vB.z * Si + vB.w * Di;
        }
    }
    #pragma unroll
    for (int li = 0; li < 4; ++li) {
        const float a00r = acc[li][0] * dt, a00i = acc[li][1] * dt;
        const float a01r = acc[li][2] * dt, a01i = acc[li][3] * dt;
        const float a10r = acc[li][4] * dt, a10i = acc[li][5] * dt;
        const float a11r = acc[li][6] * dt, a11i = acc[li][7] * dt;
        const float numr = a01r * a10r - a01i * a10i;
        const float numi = a01r * a10i + a01i * a10r;
        const float dwr = 1.f + a11r, dwi = a11i;
        const float idw = __builtin_amdgcn_rcpf(dwr * dwr + dwi * dwi);
        const float qr = (numr * dwr + numi * dwi) * idw;
        const float qi = (numi * dwr - numr * dwi) * idw;
        const float kfr = a00r - qr, kfi = a00i - qi;
        const float fi  = 0.5f * yv[li];
        s_G[tid + NT * li] = make_float2(kfr - kfi * fi, kfi + kfr * fi);
    }

    // ---- Phase 1b: Nyquist bin l=4096, one pole per lane of wave 0 ----
    if (tid < 64) {
        const int n = tid;
        const float4 wd = s_wd[n];
        const float4 vA = s_v[2 * n];
        const float4 vB = s_v[2 * n + 1];
        float s, c;
        sincosf(3.8349519697141031e-4f * 4096.0f, &s, &c);
        const float y  = 2.0f * s * __builtin_amdgcn_rcpf(c);
        const float t1 = y - wd.y, t2 = y + wd.y;
        const float i1 = __builtin_amdgcn_rcpf(fmaf(t1, t1, wd.z));
        const float i2 = __builtin_amdgcn_rcpf(fmaf(t2, t2, wd.z));
        const float u1 = t1 * i1, u2 = t2 * i2;
        const float Sr = wd.x * (i1 + i2);
        const float Si = -(u1 + u2);
        const float Dr = u1 - u2;
        const float Di = wd.x * (i1 - i2);
        float e[8];
        e[0] = vA.x * Sr + vA.y * Dr;
        e[1] = vA.x * Si + vA.y * Di;
        e[2] = vA.z * Sr + vA.w * Dr;
        e[3] = vA.z * Si + vA.w * Di;
        e[4] = vB.x * Sr + vB.y * Dr;
        e[5] = vB.x * Si + vB.y * Di;
        e[6] = vB.z * Sr + vB.w * Dr;
        e[7] = vB.z * Si + vB.w * Di;
        #pragma unroll
        for (int m = 1; m < 64; m <<= 1) {
            #pragma unroll
            for (int t = 0; t < 8; ++t) e[t] += __shfl_xor(e[t], m);
        }
        if (tid == 0) {
            const float a00r = e[0] * dt, a00i = e[1] * dt;
            const float a01r = e[2] * dt, a01i = e[3] * dt;
            const float a10r = e[4] * dt, a10i = e[5] * dt;
            const float a11r = e[6] * dt, a11i = e[7] * dt;
            const float numr = a01r * a10r - a01i * a10i;
            const float numi = a01r * a10i + a01i * a10r;
            const float dwr = 1.f + a11r, dwi = a11i;
            const float idw = __builtin_amdgcn_rcpf(dwr * dwr + dwi * dwi);
            const float qr = (numr * dwr + numi * dwi) * idw;
            const float qi = (numi * dwr - numr * dwi) * idw;
            const float kfr = a00r - qr, kfi = a00i - qi;
            const float fi  = 0.5f * y;
            s_G[NHALF] = make_float2(kfr - kfi * fi, kfi + kfr * fi);
        }
    }
    __syncthreads();

    // ---- Phase 2: pack irfft(L) into complex iFFT(L/2), natural order ----
    // Z[k] = (1/L)[(G[k]+conj(G[N-k])) + i*e^{+2pi i k/L}(G[k]-conj(G[N-k]))]
    #pragma unroll
    for (int ki = 0; ki < 4; ++ki) {
        const int k = tid + NT * ki;
        const float2 Gk = s_G[k];
        const float2 Gn = s_G[NHALF - k];
        const float Ar = Gk.x + Gn.x, Ai = Gk.y - Gn.y;
        const float Br = Gk.x - Gn.x, Bi = Gk.y + Gn.y;
        const float2 t8 = s_T8[k & 2047];
        const bool  hi = (k >= 2048);
        const float cw = hi ? -t8.y : t8.x;
        const float sw = hi ?  t8.x : t8.y;
        const float sc = 1.0f / (float)LL;
        s_Z[k] = make_float2((Ar - cw * Bi - sw * Br) * sc,
                             (Ai + cw * Br - sw * Bi) * sc);
    }
    __syncthreads();

    // ---- Phase 3: radix-4 Stockham inverse FFT (sign +1), 6 stages ----
    {
        float2* pin  = s_Z;
        float2* pout = s_G;
        #pragma unroll
        for (int s = 0; s < 6; ++s) {
            const int ls2 = 2 * s;
            const int Ls  = 1 << ls2;
            const int j   = tid;                 // one butterfly per thread
            const int k   = j & (Ls - 1);
            const int tb  = k << (10 - ls2);
            const float2 w1 = s_T4[tb];
            const float2 w2 = s_T4[2 * tb];
            float2 u0 = pin[j];
            float2 u1 = pin[j + 1024];
            float2 u2 = pin[j + 2048];
            float2 u3 = pin[j + 3072];
            const float w3r = w1.x * w2.x - w1.y * w2.y;
            const float w3i = w1.x * w2.y + w1.y * w2.x;
            float a, b;
            a = u1.x * w1.x - u1.y * w1.y;  b = u1.x * w1.y + u1.y * w1.x;  u1 = make_float2(a, b);
            a = u2.x * w2.x - u2.y * w2.y;  b = u2.x * w2.y + u2.y * w2.x;  u2 = make_float2(a, b);
            a = u3.x * w3r  - u3.y * w3i;   b = u3.x * w3i  + u3.y * w3r;   u3 = make_float2(a, b);
            const float t0r = u0.x + u2.x, t0i = u0.y + u2.y;
            const float t1r = u0.x - u2.x, t1i = u0.y - u2.y;
            const float t2r = u1.x + u3.x, t2i = u1.y + u3.y;
            const float t3r = u3.y - u1.y, t3i = u1.x - u3.x;   // i*(u1-u3)
            const int ob = ((j - k) << 2) + k;
            pout[ob]          = make_float2(t0r + t2r, t0i + t2i);
            pout[ob + Ls]     = make_float2(t1r + t3r, t1i + t3i);
            pout[ob + 2 * Ls] = make_float2(t0r - t2r, t0i - t2i);
            pout[ob + 3 * Ls] = make_float2(t1r - t3r, t1i - t3i);
            float2* tmp = pin; pin = pout; pout = tmp;
            __syncthreads();
        }
    }

    // ---- Phase 4: x[2j]=Re, x[2j+1]=Im; coalesced float2 store ----
    float2* orow = (float2*)(out + (size_t)h * LL);
    #pragma unroll
    for (int ji = 0; ji < 4; ++ji) {
        const int j = tid + NT * ji;
        orow[j] = s_Z[j];
    }
}

extern "C" void kernel_launch(void* const* d_in, const int* in_sizes, int n_in,
                              void* d_out, int out_size, void* d_ws, size_t ws_size,
                              hipStream_t stream) {
    const float* w   = (const float*)d_in[0];
    const float* p   = (const float*)d_in[1];
    const float* q   = (const float*)d_in[2];
    const float* B   = (const float*)d_in[3];
    const float* C   = (const float*)d_in[4];
    const float* ldt = (const float*)d_in[5];
    ssk_nplr_kernel<<<NUM_H, NT, 0, stream>>>(w, p, q, B, C, ldt, (float*)d_out);
}

// Round 3
// 81.225 us; speedup vs baseline: 3.8420x; 3.8420x over previous
//
#include <hip/hip_runtime.h>
#include <math.h>

#define NUM_H 256
#define NP    64        // poles per h
#define LL    8192      // sequence length
#define NHALF 4096      // LL/2 (complex FFT size)
#define NTA   512       // threads, Cauchy kernel
#define NTB   1024      // threads, FFT kernel

// v_sin_f32 / v_cos_f32 take input in REVOLUTIONS (D = sin(S0 * 2pi)).

// ---------------- Kernel A: Cauchy sum + Woodbury -> spectrum ----------------
__global__ __launch_bounds__(NTA, 8)
void cauchy_phase(const float* __restrict__ w_ri,
                  const float* __restrict__ p_ri,
                  const float* __restrict__ q_ri,
                  const float* __restrict__ B_ri,
                  const float* __restrict__ C_ri,
                  const float* __restrict__ log_dt,
                  float*       __restrict__ spec,   // (H, 4096) float2 rows (= d_out)
                  float2*      __restrict__ nyq)    // (H,) Nyquist bins (= d_ws)
{
    __shared__ float4 s_wd[NP];       // (-wr*dt, wi*dt, (wr*dt)^2, 0)
    __shared__ float4 s_v[NP * 2];    // {v00r,v00i,v01r,v01i},{v10r,v10i,v11r,v11i}

    const int h     = blockIdx.y;
    const int chunk = blockIdx.x;     // 4 chunks of 1024 bins
    const int tid   = threadIdx.x;
    const float dt  = expf(log_dt[h]);

    if (tid < NP) {
        const int n = tid;
        const float2 w = ((const float2*)w_ri)[h * NP + n];
        const float2 p = ((const float2*)p_ri)[h * NP + n];
        const float2 q = ((const float2*)q_ri)[h * NP + n];
        const float2 B = ((const float2*)B_ri)[h * NP + n];
        const float2 C = ((const float2*)C_ri)[h * NP + n];
        const float wr = w.x * dt, wi = w.y * dt;
        s_wd[n] = make_float4(-wr, wi, wr * wr, 0.f);
        float4 vA, vB;
        vA.x = B.x * C.x + B.y * C.y;  vA.y = B.y * C.x - B.x * C.y;  // B*conj(C)
        vA.z = p.x * C.x + p.y * C.y;  vA.w = p.y * C.x - p.x * C.y;  // p*conj(C)
        vB.x = B.x * q.x + B.y * q.y;  vB.y = B.y * q.x - B.x * q.y;  // B*conj(q)
        vB.z = p.x * q.x + p.y * q.y;  vB.w = p.y * q.x - p.x * q.y;  // p*conj(q)
        s_v[2 * n]     = vA;
        s_v[2 * n + 1] = vB;
    }
    __syncthreads();

    float2* grow = (float2*)(spec + (size_t)h * LL);

    #pragma unroll
    for (int li = 0; li < 2; ++li) {
        const int l = (chunk << 10) + (li << 9) + tid;   // 0..4095
        // y = Im(z) = 2*tan(pi*l/L); rev = l/16384 (exact dyadic)
        const float rev = (float)l * 6.103515625e-5f;
        const float sn  = __builtin_amdgcn_sinf(rev);
        float       cn  = __builtin_amdgcn_cosf(rev);
        cn = fmaxf(cn, 4.3711388e-8f);
        const float y   = 2.0f * sn * __builtin_amdgcn_rcpf(cn);

        float a0 = 0.f, a1 = 0.f, a2 = 0.f, a3 = 0.f;
        float a4 = 0.f, a5 = 0.f, a6 = 0.f, a7 = 0.f;
        #pragma unroll 8
        for (int n = 0; n < NP; ++n) {
            const float4 wd = s_wd[n];
            const float4 vA = s_v[2 * n];
            const float4 vB = s_v[2 * n + 1];
            const float t1 = y - wd.y, t2 = y + wd.y;
            const float i1 = __builtin_amdgcn_rcpf(fmaf(t1, t1, wd.z));
            const float i2 = __builtin_amdgcn_rcpf(fmaf(t2, t2, wd.z));
            const float u1 = t1 * i1, u2 = t2 * i2;
            const float Sr = wd.x * (i1 + i2);
            const float Si = -(u1 + u2);
            const float Dr = u1 - u2;
            const float Di = wd.x * (i1 - i2);
            a0 += vA.x * Sr + vA.y * Dr;   a1 += vA.x * Si + vA.y * Di;
            a2 += vA.z * Sr + vA.w * Dr;   a3 += vA.z * Si + vA.w * Di;
            a4 += vB.x * Sr + vB.y * Dr;   a5 += vB.x * Si + vB.y * Di;
            a6 += vB.z * Sr + vB.w * Dr;   a7 += vB.z * Si + vB.w * Di;
        }
        const float a00r = a0 * dt, a00i = a1 * dt;
        const float a01r = a2 * dt, a01i = a3 * dt;
        const float a10r = a4 * dt, a10i = a5 * dt;
        const float a11r = a6 * dt, a11i = a7 * dt;
        const float numr = a01r * a10r - a01i * a10i;
        const float numi = a01r * a10i + a01i * a10r;
        const float dwr = 1.f + a11r, dwi = a11i;
        const float idw = __builtin_amdgcn_rcpf(dwr * dwr + dwi * dwi);
        const float qr = (numr * dwr + numi * dwi) * idw;
        const float qi = (numi * dwr - numr * dwi) * idw;
        const float kfr = a00r - qr, kfi = a00i - qi;
        const float fi  = 0.5f * y;        // 2/(1+nodes) = 1 + i*tan(pi*l/L)
        grow[l] = make_float2(kfr - kfi * fi, kfi + kfr * fi);
    }

    // ---- Nyquist bin l=4096: one pole per lane of wave 0 of chunk 3 ----
    if (chunk == 3 && tid < 64) {
        const int n = tid;
        const float4 wd = s_wd[n];
        const float4 vA = s_v[2 * n];
        const float4 vB = s_v[2 * n + 1];
        // rev = 0.25 -> cos = 0 exactly; clamp reproduces reference's f32 z ~ 4.58e7
        const float y  = 2.0f * __builtin_amdgcn_rcpf(4.3711388e-8f);
        const float t1 = y - wd.y, t2 = y + wd.y;
        const float i1 = __builtin_amdgcn_rcpf(fmaf(t1, t1, wd.z));
        const float i2 = __builtin_amdgcn_rcpf(fmaf(t2, t2, wd.z));
        const float u1 = t1 * i1, u2 = t2 * i2;
        const float Sr = wd.x * (i1 + i2);
        const float Si = -(u1 + u2);
        const float Dr = u1 - u2;
        const float Di = wd.x * (i1 - i2);
        float e0 = vA.x * Sr + vA.y * Dr, e1 = vA.x * Si + vA.y * Di;
        float e2 = vA.z * Sr + vA.w * Dr, e3 = vA.z * Si + vA.w * Di;
        float e4 = vB.x * Sr + vB.y * Dr, e5 = vB.x * Si + vB.y * Di;
        float e6 = vB.z * Sr + vB.w * Dr, e7 = vB.z * Si + vB.w * Di;
        #pragma unroll
        for (int m = 1; m < 64; m <<= 1) {
            e0 += __shfl_xor(e0, m);  e1 += __shfl_xor(e1, m);
            e2 += __shfl_xor(e2, m);  e3 += __shfl_xor(e3, m);
            e4 += __shfl_xor(e4, m);  e5 += __shfl_xor(e5, m);
            e6 += __shfl_xor(e6, m);  e7 += __shfl_xor(e7, m);
        }
        if (tid == 0) {
            const float a00r = e0 * dt, a00i = e1 * dt;
            const float a01r = e2 * dt, a01i = e3 * dt;
            const float a10r = e4 * dt, a10i = e5 * dt;
            const float a11r = e6 * dt, a11i = e7 * dt;
            const float numr = a01r * a10r - a01i * a10i;
            const float numi = a01r * a10i + a01i * a10r;
            const float dwr = 1.f + a11r, dwi = a11i;
            const float idw = __builtin_amdgcn_rcpf(dwr * dwr + dwi * dwi);
            const float qr = (numr * dwr + numi * dwi) * idw;
            const float qi = (numi * dwr - numr * dwi) * idw;
            const float kfr = a00r - qr, kfi = a00i - qi;
            const float fi  = 0.5f * y;
            nyq[h] = make_float2(kfr - kfi * fi, kfi + kfr * fi);
        }
    }
}

// ---------------- Kernel B: pack + radix-4 Stockham iFFT + store -------------
__global__ __launch_bounds__(NTB)
void ifft_phase(float* __restrict__ io, const float2* __restrict__ nyq)
{
    __shared__ float2 sA[NHALF];
    __shared__ float2 sB[NHALF];

    const int h   = blockIdx.x;
    const int tid = threadIdx.x;
    float2* grow = (float2*)(io + (size_t)h * LL);

    // pack irfft(L) into complex iFFT(L/2), natural order:
    // Z[k] = (1/L)[(G[k]+conj(G[N-k])) + i*e^{+2pi i k/L}(G[k]-conj(G[N-k]))]
    #pragma unroll
    for (int ki = 0; ki < 4; ++ki) {
        const int k = tid + NTB * ki;
        const float2 Gk = grow[k];
        const float2 Gn = (k == 0) ? nyq[h] : grow[NHALF - k];
        const float Ar = Gk.x + Gn.x, Ai = Gk.y - Gn.y;
        const float Br = Gk.x - Gn.x, Bi = Gk.y + Gn.y;
        const float rev = (float)k * 1.220703125e-4f;   // k/8192
        const float cw = __builtin_amdgcn_cosf(rev);
        const float sw = __builtin_amdgcn_sinf(rev);
        const float sc = 1.0f / (float)LL;
        sA[k] = make_float2((Ar - cw * Bi - sw * Br) * sc,
                            (Ai + cw * Br - sw * Bi) * sc);
    }
    __syncthreads();

    // 6 radix-4 Stockham stages (inverse FFT, e^{+i} twiddles), ping-pong sA<->sB
    float2* pin  = sA;
    float2* pout = sB;
    #pragma unroll
    for (int s = 0; s < 6; ++s) {
        const int ls2 = 2 * s;
        const int Ls  = 1 << ls2;
        const int j   = tid;
        const int k   = j & (Ls - 1);
        const int tb  = k << (10 - ls2);
        const float fr = (float)tb * 2.44140625e-4f;    // tb/4096 revolutions
        const float c1 = __builtin_amdgcn_cosf(fr);
        const float s1 = __builtin_amdgcn_sinf(fr);
        const float c2 = __builtin_amdgcn_cosf(2.0f * fr);
        const float s2 = __builtin_amdgcn_sinf(2.0f * fr);
        const float c3 = __builtin_amdgcn_cosf(3.0f * fr);
        const float s3 = __builtin_amdgcn_sinf(3.0f * fr);
        float2 u0 = pin[j];
        float2 u1 = pin[j + 1024];
        float2 u2 = pin[j + 2048];
        float2 u3 = pin[j + 3072];
        float a, b;
        a = u1.x * c1 - u1.y * s1;  b = u1.x * s1 + u1.y * c1;  u1 = make_float2(a, b);
        a = u2.x * c2 - u2.y * s2;  b = u2.x * s2 + u2.y * c2;  u2 = make_float2(a, b);
        a = u3.x * c3 - u3.y * s3;  b = u3.x * s3 + u3.y * c3;  u3 = make_float2(a, b);
        const float t0r = u0.x + u2.x, t0i = u0.y + u2.y;
        const float t1r = u0.x - u2.x, t1i = u0.y - u2.y;
        const float t2r = u1.x + u3.x, t2i = u1.y + u3.y;
        const float t3r = u3.y - u1.y, t3i = u1.x - u3.x;   // i*(u1-u3)
        const int ob = ((j - k) << 2) + k;
        pout[ob]          = make_float2(t0r + t2r, t0i + t2i);
        pout[ob + Ls]     = make_float2(t1r + t3r, t1i + t3i);
        pout[ob + 2 * Ls] = make_float2(t0r - t2r, t0i - t2i);
        pout[ob + 3 * Ls] = make_float2(t1r - t3r, t1i - t3i);
        float2* tmp = pin; pin = pout; pout = tmp;
        __syncthreads();
    }

    // final data lands in sA; x[2j]=Re, x[2j+1]=Im -> coalesced float2 store
    #pragma unroll
    for (int ji = 0; ji < 4; ++ji) {
        const int j = tid + NTB * ji;
        grow[j] = sA[j];
    }
}

extern "C" void kernel_launch(void* const* d_in, const int* in_sizes, int n_in,
                              void* d_out, int out_size, void* d_ws, size_t ws_size,
                              hipStream_t stream) {
    const float* w   = (const float*)d_in[0];
    const float* p   = (const float*)d_in[1];
    const float* q   = (const float*)d_in[2];
    const float* B   = (const float*)d_in[3];
    const float* C   = (const float*)d_in[4];
    const float* ldt = (const float*)d_in[5];
    float*  spec = (float*)d_out;          // spectrum staged in-place in d_out
    float2* nyq  = (float2*)d_ws;          // 256 * 8 B Nyquist bins

    dim3 gridA(4, NUM_H);
    cauchy_phase<<<gridA, NTA, 0, stream>>>(w, p, q, B, C, ldt, spec, nyq);
    ifft_phase<<<NUM_H, NTB, 0, stream>>>(spec, nyq);
}

// Round 4
// 60.981 us; speedup vs baseline: 5.1175x; 1.3320x over previous
//
#include <hip/hip_runtime.h>
#include <math.h>

#define NUM_H 256
#define NP    64        // poles per h
#define LL    8192      // sequence length
#define NHALF 4096      // LL/2 (complex FFT size)
#define NTA   256       // threads, Cauchy kernel
#define NTB   1024      // threads, FFT kernel

typedef float v2f __attribute__((ext_vector_type(2)));

// v_sin_f32 / v_cos_f32 take input in REVOLUTIONS (D = sin(S0 * 2pi)).

// ---------------- Kernel A: Cauchy sum + Woodbury -> spectrum ----------------
// Packed-f32: each thread computes TWO bins (l0, l0+2048); every inner-loop op
// is a v_pk_*_f32 over the bin pair; rcp stays scalar (no packed trans).
__global__ __launch_bounds__(NTA, 6)
void cauchy_phase(const float* __restrict__ w_ri,
                  const float* __restrict__ p_ri,
                  const float* __restrict__ q_ri,
                  const float* __restrict__ B_ri,
                  const float* __restrict__ C_ri,
                  const float* __restrict__ log_dt,
                  float*       __restrict__ spec,   // (H, 4096) float2 rows (= d_out)
                  float2*      __restrict__ nyq)    // (H,) Nyquist bins (= d_ws)
{
    __shared__ float4 s_wd[NP];       // (-wr*dt, wi*dt, (wr*dt)^2, 0)
    __shared__ float4 s_v[NP * 2];    // {v00r,v00i,v01r,v01i},{v10r,v10i,v11r,v11i}

    const int h     = blockIdx.y;
    const int chunk = blockIdx.x;     // 8 chunks of 256 low bins
    const int tid   = threadIdx.x;
    const float dt  = expf(log_dt[h]);

    if (tid < NP) {
        const int n = tid;
        const float2 w = ((const float2*)w_ri)[h * NP + n];
        const float2 p = ((const float2*)p_ri)[h * NP + n];
        const float2 q = ((const float2*)q_ri)[h * NP + n];
        const float2 B = ((const float2*)B_ri)[h * NP + n];
        const float2 C = ((const float2*)C_ri)[h * NP + n];
        const float wr = w.x * dt, wi = w.y * dt;
        s_wd[n] = make_float4(-wr, wi, wr * wr, 0.f);
        float4 vA, vB;
        vA.x = B.x * C.x + B.y * C.y;  vA.y = B.y * C.x - B.x * C.y;  // B*conj(C)
        vA.z = p.x * C.x + p.y * C.y;  vA.w = p.y * C.x - p.x * C.y;  // p*conj(C)
        vB.x = B.x * q.x + B.y * q.y;  vB.y = B.y * q.x - B.x * q.y;  // B*conj(q)
        vB.z = p.x * q.x + p.y * q.y;  vB.w = p.y * q.x - p.x * q.y;  // p*conj(q)
        s_v[2 * n]     = vA;
        s_v[2 * n + 1] = vB;
    }
    __syncthreads();

    float2* grow = (float2*)(spec + (size_t)h * LL);

    const int l0 = (chunk << 8) + tid;      // 0..2047
    // y = Im(z) = 2*tan(pi*l/L);  rev = l/16384 (exact dyadic)
    v2f y2;
    {
        const float r0 = (float)l0 * 6.103515625e-5f;
        const float r1 = (float)(l0 + 2048) * 6.103515625e-5f;
        const float s0 = __builtin_amdgcn_sinf(r0);
        const float c0 = fmaxf(__builtin_amdgcn_cosf(r0), 4.3711388e-8f);
        const float s1 = __builtin_amdgcn_sinf(r1);
        const float c1 = fmaxf(__builtin_amdgcn_cosf(r1), 4.3711388e-8f);
        y2 = (v2f){2.0f * s0 * __builtin_amdgcn_rcpf(c0),
                   2.0f * s1 * __builtin_amdgcn_rcpf(c1)};
    }

    v2f a0 = 0.f, a1 = 0.f, a2 = 0.f, a3 = 0.f;
    v2f a4 = 0.f, a5 = 0.f, a6 = 0.f, a7 = 0.f;
    #pragma unroll 2
    for (int n = 0; n < NP; ++n) {
        const float4 wd = s_wd[n];
        const float4 vA = s_v[2 * n];
        const float4 vB = s_v[2 * n + 1];
        const v2f wi  = {wd.y, wd.y};
        const v2f wr2 = {wd.z, wd.z};
        const v2f wrx = {wd.x, wd.x};
        const v2f t1 = y2 - wi;
        const v2f t2 = y2 + wi;
        const v2f d1 = t1 * t1 + wr2;
        const v2f d2 = t2 * t2 + wr2;
        const v2f i1 = {__builtin_amdgcn_rcpf(d1.x), __builtin_amdgcn_rcpf(d1.y)};
        const v2f i2 = {__builtin_amdgcn_rcpf(d2.x), __builtin_amdgcn_rcpf(d2.y)};
        const v2f u1 = t1 * i1;
        const v2f u2 = t2 * i2;
        const v2f Sr = wrx * (i1 + i2);
        const v2f Si = -(u1 + u2);
        const v2f Dr = u1 - u2;
        const v2f Di = wrx * (i1 - i2);
        a0 += (v2f){vA.x, vA.x} * Sr + (v2f){vA.y, vA.y} * Dr;
        a1 += (v2f){vA.x, vA.x} * Si + (v2f){vA.y, vA.y} * Di;
        a2 += (v2f){vA.z, vA.z} * Sr + (v2f){vA.w, vA.w} * Dr;
        a3 += (v2f){vA.z, vA.z} * Si + (v2f){vA.w, vA.w} * Di;
        a4 += (v2f){vB.x, vB.x} * Sr + (v2f){vB.y, vB.y} * Dr;
        a5 += (v2f){vB.x, vB.x} * Si + (v2f){vB.y, vB.y} * Di;
        a6 += (v2f){vB.z, vB.z} * Sr + (v2f){vB.w, vB.w} * Dr;
        a7 += (v2f){vB.z, vB.z} * Si + (v2f){vB.w, vB.w} * Di;
    }

    #pragma unroll
    for (int b = 0; b < 2; ++b) {
        const int l = l0 + (b << 11);
        const float a00r = a0[b] * dt, a00i = a1[b] * dt;
        const float a01r = a2[b] * dt, a01i = a3[b] * dt;
        const float a10r = a4[b] * dt, a10i = a5[b] * dt;
        const float a11r = a6[b] * dt, a11i = a7[b] * dt;
        const float numr = a01r * a10r - a01i * a10i;
        const float numi = a01r * a10i + a01i * a10r;
        const float dwr = 1.f + a11r, dwi = a11i;
        const float idw = __builtin_amdgcn_rcpf(dwr * dwr + dwi * dwi);
        const float qr = (numr * dwr + numi * dwi) * idw;
        const float qi = (numi * dwr - numr * dwi) * idw;
        const float kfr = a00r - qr, kfi = a00i - qi;
        const float fi  = 0.5f * y2[b];     // 2/(1+nodes) = 1 + i*tan(pi*l/L)
        grow[l] = make_float2(kfr - kfi * fi, kfi + kfr * fi);
    }

    // ---- Nyquist bin l=4096: one pole per lane of wave 0 of chunk 7 ----
    if (chunk == 7 && tid < 64) {
        const int n = tid;
        const float4 wd = s_wd[n];
        const float4 vA = s_v[2 * n];
        const float4 vB = s_v[2 * n + 1];
        // rev = 0.25 -> cos = 0 exactly; clamp reproduces reference's f32 z ~ 4.58e7
        const float y  = 2.0f * __builtin_amdgcn_rcpf(4.3711388e-8f);
        const float t1 = y - wd.y, t2 = y + wd.y;
        const float i1 = __builtin_amdgcn_rcpf(fmaf(t1, t1, wd.z));
        const float i2 = __builtin_amdgcn_rcpf(fmaf(t2, t2, wd.z));
        const float u1 = t1 * i1, u2 = t2 * i2;
        const float Sr = wd.x * (i1 + i2);
        const float Si = -(u1 + u2);
        const float Dr = u1 - u2;
        const float Di = wd.x * (i1 - i2);
        float e0 = vA.x * Sr + vA.y * Dr, e1 = vA.x * Si + vA.y * Di;
        float e2 = vA.z * Sr + vA.w * Dr, e3 = vA.z * Si + vA.w * Di;
        float e4 = vB.x * Sr + vB.y * Dr, e5 = vB.x * Si + vB.y * Di;
        float e6 = vB.z * Sr + vB.w * Dr, e7 = vB.z * Si + vB.w * Di;
        #pragma unroll
        for (int m = 1; m < 64; m <<= 1) {
            e0 += __shfl_xor(e0, m);  e1 += __shfl_xor(e1, m);
            e2 += __shfl_xor(e2, m);  e3 += __shfl_xor(e3, m);
            e4 += __shfl_xor(e4, m);  e5 += __shfl_xor(e5, m);
            e6 += __shfl_xor(e6, m);  e7 += __shfl_xor(e7, m);
        }
        if (tid == 0) {
            const float a00r = e0 * dt, a00i = e1 * dt;
            const float a01r = e2 * dt, a01i = e3 * dt;
            const float a10r = e4 * dt, a10i = e5 * dt;
            const float a11r = e6 * dt, a11i = e7 * dt;
            const float numr = a01r * a10r - a01i * a10i;
            const float numi = a01r * a10i + a01i * a10r;
            const float dwr = 1.f + a11r, dwi = a11i;
            const float idw = __builtin_amdgcn_rcpf(dwr * dwr + dwi * dwi);
            const float qr = (numr * dwr + numi * dwi) * idw;
            const float qi = (numi * dwr - numr * dwi) * idw;
            const float kfr = a00r - qr, kfi = a00i - qi;
            const float fi  = 0.5f * y;
            nyq[h] = make_float2(kfr - kfi * fi, kfi + kfr * fi);
        }
    }
}

// ---------------- Kernel B: pack + radix-4 Stockham iFFT + store -------------
__global__ __launch_bounds__(NTB)
void ifft_phase(float* __restrict__ io, const float2* __restrict__ nyq)
{
    __shared__ float2 sA[NHALF];
    __shared__ float2 sB[NHALF];

    const int h   = blockIdx.x;
    const int tid = threadIdx.x;
    float2* grow = (float2*)(io + (size_t)h * LL);

    // pack irfft(L) into complex iFFT(L/2), natural order:
    // Z[k] = (1/L)[(G[k]+conj(G[N-k])) + i*e^{+2pi i k/L}(G[k]-conj(G[N-k]))]
    #pragma unroll
    for (int ki = 0; ki < 4; ++ki) {
        const int k = tid + NTB * ki;
        const float2 Gk = grow[k];
        const float2 Gn = (k == 0) ? nyq[h] : grow[NHALF - k];
        const float Ar = Gk.x + Gn.x, Ai = Gk.y - Gn.y;
        const float Br = Gk.x - Gn.x, Bi = Gk.y + Gn.y;
        const float rev = (float)k * 1.220703125e-4f;   // k/8192
        const float cw = __builtin_amdgcn_cosf(rev);
        const float sw = __builtin_amdgcn_sinf(rev);
        const float sc = 1.0f / (float)LL;
        sA[k] = make_float2((Ar - cw * Bi - sw * Br) * sc,
                            (Ai + cw * Br - sw * Bi) * sc);
    }
    __syncthreads();

    // 6 radix-4 Stockham stages (inverse FFT, e^{+i} twiddles), ping-pong sA<->sB
    float2* pin  = sA;
    float2* pout = sB;
    #pragma unroll
    for (int s = 0; s < 6; ++s) {
        const int ls2 = 2 * s;
        const int Ls  = 1 << ls2;
        const int j   = tid;
        const int k   = j & (Ls - 1);
        const int tb  = k << (10 - ls2);
        const float fr = (float)tb * 2.44140625e-4f;    // tb/4096 revolutions
        const float c1 = __builtin_amdgcn_cosf(fr);
        const float s1 = __builtin_amdgcn_sinf(fr);
        const float c2 = __builtin_amdgcn_cosf(2.0f * fr);
        const float s2 = __builtin_amdgcn_sinf(2.0f * fr);
        const float c3 = __builtin_amdgcn_cosf(3.0f * fr);
        const float s3 = __builtin_amdgcn_sinf(3.0f * fr);
        float2 u0 = pin[j];
        float2 u1 = pin[j + 1024];
        float2 u2 = pin[j + 2048];
        float2 u3 = pin[j + 3072];
        float a, b;
        a = u1.x * c1 - u1.y * s1;  b = u1.x * s1 + u1.y * c1;  u1 = make_float2(a, b);
        a = u2.x * c2 - u2.y * s2;  b = u2.x * s2 + u2.y * c2;  u2 = make_float2(a, b);
        a = u3.x * c3 - u3.y * s3;  b = u3.x * s3 + u3.y * c3;  u3 = make_float2(a, b);
        const float t0r = u0.x + u2.x, t0i = u0.y + u2.y;
        const float t1r = u0.x - u2.x, t1i = u0.y - u2.y;
        const float t2r = u1.x + u3.x, t2i = u1.y + u3.y;
        const float t3r = u3.y - u1.y, t3i = u1.x - u3.x;   // i*(u1-u3)
        const int ob = ((j - k) << 2) + k;
        pout[ob]          = make_float2(t0r + t2r, t0i + t2i);
        pout[ob + Ls]     = make_float2(t1r + t3r, t1i + t3i);
        pout[ob + 2 * Ls] = make_float2(t0r - t2r, t0i - t2i);
        pout[ob + 3 * Ls] = make_float2(t1r - t3r, t1i - t3i);
        float2* tmp = pin; pin = pout; pout = tmp;
        __syncthreads();
    }

    // final data lands in sA; x[2j]=Re, x[2j+1]=Im -> coalesced float2 store
    #pragma unroll
    for (int ji = 0; ji < 4; ++ji) {
        const int j = tid + NTB * ji;
        grow[j] = sA[j];
    }
}

extern "C" void kernel_launch(void* const* d_in, const int* in_sizes, int n_in,
                              void* d_out, int out_size, void* d_ws, size_t ws_size,
                              hipStream_t stream) {
    const float* w   = (const float*)d_in[0];
    const float* p   = (const float*)d_in[1];
    const float* q   = (const float*)d_in[2];
    const float* B   = (const float*)d_in[3];
    const float* C   = (const float*)d_in[4];
    const float* ldt = (const float*)d_in[5];
    float*  spec = (float*)d_out;          // spectrum staged in-place in d_out
    float2* nyq  = (float2*)d_ws;          // 256 * 8 B Nyquist bins

    dim3 gridA(8, NUM_H);
    cauchy_phase<<<gridA, NTA, 0, stream>>>(w, p, q, B, C, ldt, spec, nyq);
    ifft_phase<<<NUM_H, NTB, 0, stream>>>(spec, nyq);
}